// Round 8
// baseline (460.220 us; speedup 1.0000x reference)
//
#include <hip/hip_runtime.h>
#include <math.h>

#define N_ROWS 131072   // 32*64*64
#define D 64
#define K 512
#define BLK 256
#define ROWS_PER_BLK 512              // 2 rows per thread
#define GRID (N_ROWS / ROWS_PER_BLK)  // 256 blocks -> 1 per CU
#define EPAD 17                       // codebook row stride in float4s (68 floats)

// d_out layout (floats):
//   [0]                     loss
//   [1 .. 8388608]          quantized_st, NCHW [32,64,64,64]
//   [8388609]               perplexity
//   [8388610 .. +67108863]  encodings [131072, 512]
//
// d_ws layout (bytes):
//   [0, 2048)      unsigned int counts[512]
//   [2048, 2056)   unsigned long long loss_acc (fixed-point 2^-30, deterministic)
//   [4096, 6144)   float e2[512]

__global__ __launch_bounds__(256) void vq_e2_kernel(
    const float* __restrict__ emb, float* __restrict__ e2)
{
    int k = blockIdx.x * blockDim.x + threadIdx.x;
    if (k < K) {
        const float* e = emb + k * D;
        float s = 0.f;
        #pragma unroll
        for (int d = 0; d < D; ++d) s = fmaf(e[d], e[d], s);
        e2[k] = s;
    }
}

// Round-7 lesson: distance loop is LDS read-instruction bound (16 broadcast
// ds_read_b128 per wave per k; ~12 cyc each on the one LDS pipe/CU; 8 waves
// -> ~1500 cyc/k vs 288 cyc VALU). Fix: 2 rows/thread halves LDS instrs per
// FMA; stride-pad EPAD=17 kills the WQ-phase same-bank reads; e2 in LDS.
#define FOR16(M) M(0) M(1) M(2) M(3) M(4) M(5) M(6) M(7) \
                 M(8) M(9) M(10) M(11) M(12) M(13) M(14) M(15)

__global__ __launch_bounds__(BLK, 1) void vq_main_kernel(
    const float* __restrict__ in,     // [32,64,64,64] NCHW
    const float* __restrict__ emb,    // [512,64]
    const float* __restrict__ e2,     // [512]
    unsigned int* __restrict__ counts,
    unsigned long long* __restrict__ loss_acc,
    float* __restrict__ quant_out,    // NCHW
    float* __restrict__ enc_out)      // [N_ROWS, 512]
{
    __shared__ float s_emb[K * EPAD * 4];   // 139264 B, padded stride
    __shared__ float s_e2[K];               // 2 KB
    __shared__ int s_idx[ROWS_PER_BLK];     // 2 KB
    __shared__ unsigned int s_hist[K];      // 2 KB
    __shared__ double s_red[BLK];           // 2 KB

    const int tid = threadIdx.x;
    const int n0 = blockIdx.x * ROWS_PER_BLK + tid;        // row A
    const int n1 = n0 + BLK;                               // row B
    const int b0 = n0 >> 12, hw0 = n0 & 4095;
    const int b1 = n1 >> 12, hw1 = n1 & 4095;
    const float* xinA = in + (size_t)b0 * 262144 + hw0;
    const float* xinB = in + (size_t)b1 * 262144 + hw1;

    // stage codebook -> LDS (padded rows), e2 -> LDS, zero histogram
    {
        const float4* g4 = reinterpret_cast<const float4*>(emb);
        float4* l4 = reinterpret_cast<float4*>(s_emb);
        #pragma unroll
        for (int j = tid; j < K * 16; j += BLK)
            l4[(j >> 4) * EPAD + (j & 15)] = g4[j];
        for (int j = tid; j < K; j += BLK) { s_e2[j] = e2[j]; s_hist[j] = 0; }
    }

    // load both x rows into named registers (coalesced across lanes per d),
    // pinned via opaque asm so they cannot be sunk back into the k-loop.
#define LOADX(i) \
    float4 xA##i = make_float4(xinA[(4*i+0)*4096], xinA[(4*i+1)*4096], \
                               xinA[(4*i+2)*4096], xinA[(4*i+3)*4096]); \
    float4 xB##i = make_float4(xinB[(4*i+0)*4096], xinB[(4*i+1)*4096], \
                               xinB[(4*i+2)*4096], xinB[(4*i+3)*4096]);
    FOR16(LOADX)
#undef LOADX
#define PINX(i) asm volatile("" : "+v"(xA##i.x), "+v"(xA##i.y), \
                                  "+v"(xA##i.z), "+v"(xA##i.w), \
                                  "+v"(xB##i.x), "+v"(xB##i.y), \
                                  "+v"(xB##i.z), "+v"(xB##i.w));
    FOR16(PINX)
#undef PINX

    __syncthreads();

    // argmin over codes for both rows: score = ||e||^2 - 2 x.e
    float s1a = INFINITY, s2a = INFINITY, s1b = INFINITY, s2b = INFINITY;
    int i1a = 0, i2a = 0, i1b = 0, i2b = 0;
    for (int k = 0; k < K; ++k) {
        const float4* __restrict__ e4 =
            reinterpret_cast<const float4*>(s_emb) + k * EPAD;
        float a0 = 0.f, a1 = 0.f, a2 = 0.f, a3 = 0.f;
        float c0 = 0.f, c1 = 0.f, c2 = 0.f, c3 = 0.f;
#define FMA2(i) { float4 ev = e4[i]; \
                  a0 = fmaf(xA##i.x, ev.x, a0); \
                  a1 = fmaf(xA##i.y, ev.y, a1); \
                  a2 = fmaf(xA##i.z, ev.z, a2); \
                  a3 = fmaf(xA##i.w, ev.w, a3); \
                  c0 = fmaf(xB##i.x, ev.x, c0); \
                  c1 = fmaf(xB##i.y, ev.y, c1); \
                  c2 = fmaf(xB##i.z, ev.z, c2); \
                  c3 = fmaf(xB##i.w, ev.w, c3); }
        FOR16(FMA2)
#undef FMA2
        float ek = s_e2[k];
        float sa = fmaf(-2.f, (a0 + a1) + (a2 + a3), ek);
        float sb = fmaf(-2.f, (c0 + c1) + (c2 + c3), ek);
        if (sa < s1a) { s2a = s1a; i2a = i1a; s1a = sa; i1a = k; }
        else if (sa < s2a) { s2a = sa; i2a = k; }
        if (sb < s1b) { s2b = s1b; i2b = i1b; s1b = sb; i1b = k; }
        else if (sb < s2b) { s2b = sb; i2b = k; }
    }

    // fp64 refinement when top-2 nearly tie (makes argmin fp64-exact)
#define REFQ(v, off) { \
        double t; \
        t = (double)(v).x - (double)eA[(off)+0]; dA = fma(t, t, dA); \
        t = (double)(v).x - (double)eB[(off)+0]; dB = fma(t, t, dB); \
        t = (double)(v).y - (double)eA[(off)+1]; dA = fma(t, t, dA); \
        t = (double)(v).y - (double)eB[(off)+1]; dB = fma(t, t, dB); \
        t = (double)(v).z - (double)eA[(off)+2]; dA = fma(t, t, dA); \
        t = (double)(v).z - (double)eB[(off)+2]; dB = fma(t, t, dB); \
        t = (double)(v).w - (double)eA[(off)+3]; dA = fma(t, t, dA); \
        t = (double)(v).w - (double)eB[(off)+3]; dB = fma(t, t, dB); }
    if (s2a - s1a < 4e-3f) {
        const float* eA = s_emb + i1a * (EPAD * 4);
        const float* eB = s_emb + i2a * (EPAD * 4);
        double dA = 0.0, dB = 0.0;
#define RA(i) REFQ(xA##i, 4*i)
        FOR16(RA)
#undef RA
        if (dB < dA || (dB == dA && i2a < i1a)) i1a = i2a;
    }
    if (s2b - s1b < 4e-3f) {
        const float* eA = s_emb + i1b * (EPAD * 4);
        const float* eB = s_emb + i2b * (EPAD * 4);
        double dA = 0.0, dB = 0.0;
#define RB(i) REFQ(xB##i, 4*i)
        FOR16(RB)
#undef RB
        if (dB < dA || (dB == dA && i2b < i1b)) i1b = i2b;
    }
#undef REFQ

    s_idx[tid] = i1a;
    s_idx[tid + BLK] = i1b;
    atomicAdd(&s_hist[i1a], 1u);
    atomicAdd(&s_hist[i1b], 1u);

    // quantized writes (NCHW, coalesced across lanes per d) + loss partial
    float lsum = 0.f;
    {
        const float4* __restrict__ eq4 =
            reinterpret_cast<const float4*>(s_emb) + i1a * EPAD;
        float* qout = quant_out + (size_t)b0 * 262144 + hw0;
#define WQ(i) { float4 q = eq4[i]; \
                float d0 = q.x - xA##i.x; lsum = fmaf(d0, d0, lsum); \
                float d1 = q.y - xA##i.y; lsum = fmaf(d1, d1, lsum); \
                float d2 = q.z - xA##i.z; lsum = fmaf(d2, d2, lsum); \
                float d3 = q.w - xA##i.w; lsum = fmaf(d3, d3, lsum); \
                qout[(4*i+0)*4096] = q.x; qout[(4*i+1)*4096] = q.y; \
                qout[(4*i+2)*4096] = q.z; qout[(4*i+3)*4096] = q.w; }
        FOR16(WQ)
#undef WQ
    }
    {
        const float4* __restrict__ eq4 =
            reinterpret_cast<const float4*>(s_emb) + i1b * EPAD;
        float* qout = quant_out + (size_t)b1 * 262144 + hw1;
#define WQ(i) { float4 q = eq4[i]; \
                float d0 = q.x - xB##i.x; lsum = fmaf(d0, d0, lsum); \
                float d1 = q.y - xB##i.y; lsum = fmaf(d1, d1, lsum); \
                float d2 = q.z - xB##i.z; lsum = fmaf(d2, d2, lsum); \
                float d3 = q.w - xB##i.w; lsum = fmaf(d3, d3, lsum); \
                qout[(4*i+0)*4096] = q.x; qout[(4*i+1)*4096] = q.y; \
                qout[(4*i+2)*4096] = q.z; qout[(4*i+3)*4096] = q.w; }
        FOR16(WQ)
#undef WQ
    }

    // block loss reduction (double), one deterministic fixed-point atomic
    s_red[tid] = (double)lsum;
    __syncthreads();
    for (int s = BLK / 2; s > 0; s >>= 1) {
        if (tid < s) s_red[tid] += s_red[tid + s];
        __syncthreads();
    }
    if (tid == 0) {
        unsigned long long q =
            (unsigned long long)(long long)llrint(s_red[0] * 1073741824.0);
        atomicAdd(loss_acc, q);
    }

    // flush histogram (integer atomics: deterministic)
    for (int k = tid; k < K; k += BLK) {
        unsigned int c = s_hist[k];
        if (c) atomicAdd(&counts[k], c);
    }

    // cooperative coalesced one-hot writes: 512 rows x 512 floats.
    // 2 groups of 128 threads; each group covers one row per step (float4).
    float* enc = enc_out + (size_t)blockIdx.x * (size_t)(ROWS_PER_BLK * K);
    const int grp = tid >> 7;           // 0 or 1
    const int col4 = (tid & 127) * 4;   // column start within row
    for (int rr = 0; rr < ROWS_PER_BLK; rr += 2) {
        int row = rr + grp;
        int ir = s_idx[row];
        float4 v;
        v.x = (col4 + 0 == ir) ? 1.f : 0.f;
        v.y = (col4 + 1 == ir) ? 1.f : 0.f;
        v.z = (col4 + 2 == ir) ? 1.f : 0.f;
        v.w = (col4 + 3 == ir) ? 1.f : 0.f;
        *reinterpret_cast<float4*>(enc + (size_t)row * K + col4) = v;
    }
}

__global__ __launch_bounds__(512) void vq_final_kernel(
    const unsigned int* __restrict__ counts,
    const unsigned long long* __restrict__ loss_acc,
    float* __restrict__ out_loss,
    float* __restrict__ out_perp)
{
    __shared__ double sp[512];
    int t = threadIdx.x;
    double p = (double)counts[t] / (double)N_ROWS;
    sp[t] = p * log(p + 1e-10);
    __syncthreads();
    for (int s = 256; s > 0; s >>= 1) {
        if (t < s) sp[t] += sp[t + s];
        __syncthreads();
    }
    if (t == 0) {
        double ls = (double)(long long)(*loss_acc) * (1.0 / 1073741824.0);
        *out_loss = (float)(0.25 * ls / 8388608.0);
        *out_perp = (float)exp(-sp[0]);
    }
}

extern "C" void kernel_launch(void* const* d_in, const int* in_sizes, int n_in,
                              void* d_out, int out_size, void* d_ws, size_t ws_size,
                              hipStream_t stream) {
    const float* in  = (const float*)d_in[0];
    const float* emb = (const float*)d_in[1];
    float* out = (float*)d_out;

    unsigned int* counts = (unsigned int*)d_ws;
    unsigned long long* loss_acc = (unsigned long long*)((char*)d_ws + 2048);
    float* e2 = (float*)((char*)d_ws + 4096);

    hipMemsetAsync(d_ws, 0, 2056, stream);
    vq_e2_kernel<<<2, 256, 0, stream>>>(emb, e2);
    vq_main_kernel<<<GRID, BLK, 0, stream>>>(in, emb, e2, counts, loss_acc,
                                             out + 1, out + 8388610);
    vq_final_kernel<<<1, 512, 0, stream>>>(counts, loss_acc, out, out + 8388609);
}

// Round 9
// 160.350 us; speedup vs baseline: 2.8701x; 2.8701x over previous
//
#include <hip/hip_runtime.h>
#include <math.h>

#define N_ROWS 131072   // 32*64*64
#define D 64
#define K 512
#define BLK 512                       // 8 waves
#define ROWS_PER_BLK 256              // 32 rows per wave
#define GRID (N_ROWS / ROWS_PER_BLK)  // 512
#define MARGIN 4e-3f

// d_out layout (floats):
//   [0] loss ; [1..8388608] quantized NCHW ; [8388609] perplexity ;
//   [8388610..] encodings [131072,512]
// d_ws: [0,2048) counts u32[512]; [2048,2056) loss_acc u64 fixed-point;
//       [4096,6144) e2 f32[512]

typedef __attribute__((ext_vector_type(8))) _Float16 f16x8;
typedef __attribute__((ext_vector_type(4))) float    f32x4;

#define MFMA(a, b, c) __builtin_amdgcn_mfma_f32_16x16x32_f16((a), (b), (c), 0, 0, 0)

// LDS arena (141312 B):
#define OFF_EH   0        // [512 codes][128 B] fp16-hi, XOR-swizzled
#define OFF_EL   65536    // fp16-lo
#define OFF_XH   0        // phase A: [256 rows][64] fp16-hi (overwritten by EH)
#define OFF_XL   65536    // phase A: fp16-lo (overwritten by EL)
#define OFF_E2   131072   // f32[512]
#define OFF_IDX  133120   // i32[256]
#define OFF_REF  134144   // i32[256]
#define OFF_HIST 135168   // u32[512]
#define OFF_RED  137216   // f64[512]
#define ARENA_SZ 141312

__global__ __launch_bounds__(256) void vq_e2_kernel(
    const float* __restrict__ emb, float* __restrict__ e2)
{
    int k = blockIdx.x * blockDim.x + threadIdx.x;
    if (k < K) {
        const float* e = emb + k * D;
        float s = 0.f;
        #pragma unroll
        for (int d = 0; d < D; ++d) s = fmaf(e[d], e[d], s);
        e2[k] = s;
    }
}

__device__ __forceinline__ unsigned pk2(_Float16 a, _Float16 b) {
    return (unsigned)__builtin_bit_cast(unsigned short, a) |
           ((unsigned)__builtin_bit_cast(unsigned short, b) << 16);
}

// Rounds 1-8 lesson: pure-VALU needs 64 fp32 of x live across 512 iters ->
// compiler always spills; and each wave must stream the 128KB codebook via
// its own ds_reads (16.8M ds_read_b128 total ~ 330 us floor). MFMA fixes
// both: fragments are small, and one 1KB LDS read feeds a 16x16x32 tile.
// Exact fp16 Dekker split (4 passes) gives ~fp32 score accuracy.
__global__ __launch_bounds__(BLK, 2) void vq_main_kernel(
    const float* __restrict__ in,     // [32,64,64,64] NCHW
    const float* __restrict__ emb,    // [512,64]
    const float* __restrict__ e2g,    // [512]
    unsigned int* __restrict__ counts,
    unsigned long long* __restrict__ loss_acc,
    float* __restrict__ quant_out,    // NCHW
    float* __restrict__ enc_out)      // [N_ROWS, 512]
{
    __shared__ __align__(16) char s_arena[ARENA_SZ];
    float*        e2L    = (float*)(s_arena + OFF_E2);
    int*          s_idxL = (int*)(s_arena + OFF_IDX);
    int*          s_refL = (int*)(s_arena + OFF_REF);
    unsigned int* s_hstL = (unsigned int*)(s_arena + OFF_HIST);
    double*       s_redL = (double*)(s_arena + OFF_RED);

    const int tid  = threadIdx.x;
    const int lane = tid & 63;
    const int w    = tid >> 6;      // wave 0..7
    const int fr   = lane & 15;     // frag row/col index
    const int fq   = lane >> 4;     // frag k-chunk / C row-group

    // ---- P0: stage x split into LDS [256][64] fp16 (h at XH, l at XL) ----
    {
        const int rA = tid & 255;          // row within block
        const int dh = tid >> 8;           // 0/1 -> which 32 dims
        const int d0 = dh * 32;
        const int nn = blockIdx.x * ROWS_PER_BLK + rA;
        const int bb = nn >> 12, hww = nn & 4095;
        const float* xp = in + (size_t)bb * 262144 + hww;
        char* xhW = s_arena + OFF_XH;
        char* xlW = s_arena + OFF_XL;
        #pragma unroll
        for (int i = 0; i < 32; i += 2) {
            float f0 = xp[(d0 + i) * 4096];
            float f1 = xp[(d0 + i + 1) * 4096];
            _Float16 h0 = (_Float16)f0; _Float16 l0 = (_Float16)(f0 - (float)h0);
            _Float16 h1 = (_Float16)f1; _Float16 l1 = (_Float16)(f1 - (float)h1);
            unsigned off = (unsigned)(rA * 64 + d0 + i) * 2u;
            *(unsigned*)(xhW + off) = pk2(h0, h1);
            *(unsigned*)(xlW + off) = pk2(l0, l1);
        }
    }
    __syncthreads();

    // ---- P1: each wave loads its X fragments into registers ----
    // B-frag (16x16x32): lane holds X[col = fr][k = fq*8 + i (+ks*32)]
    const _Float16* xhL = (const _Float16*)(s_arena + OFF_XH);
    const _Float16* xlL = (const _Float16*)(s_arena + OFF_XL);
    const int xr0 = w * 32 + fr;
    f16x8 xh0_0 = *(const f16x8*)(xhL + xr0 * 64 + fq * 8);
    f16x8 xh0_1 = *(const f16x8*)(xhL + xr0 * 64 + fq * 8 + 32);
    f16x8 xh1_0 = *(const f16x8*)(xhL + (xr0 + 16) * 64 + fq * 8);
    f16x8 xh1_1 = *(const f16x8*)(xhL + (xr0 + 16) * 64 + fq * 8 + 32);
    f16x8 xl0_0 = *(const f16x8*)(xlL + xr0 * 64 + fq * 8);
    f16x8 xl0_1 = *(const f16x8*)(xlL + xr0 * 64 + fq * 8 + 32);
    f16x8 xl1_0 = *(const f16x8*)(xlL + (xr0 + 16) * 64 + fq * 8);
    f16x8 xl1_1 = *(const f16x8*)(xlL + (xr0 + 16) * 64 + fq * 8 + 32);
    __syncthreads();

    // ---- P2: overwrite LDS with split codebook (XOR-swizzled rows) ----
    {
        char* eb = s_arena;
        #pragma unroll
        for (int it = 0; it < 16; ++it) {
            int j = tid + it * 512;            // float4 index, 0..8191
            int c = j >> 4, q = j & 15;        // code, quad-within-row
            float4 e = ((const float4*)emb)[j];
            _Float16 h0 = (_Float16)e.x; _Float16 l0 = (_Float16)(e.x - (float)h0);
            _Float16 h1 = (_Float16)e.y; _Float16 l1 = (_Float16)(e.y - (float)h1);
            _Float16 h2 = (_Float16)e.z; _Float16 l2 = (_Float16)(e.z - (float)h2);
            _Float16 h3 = (_Float16)e.w; _Float16 l3 = (_Float16)(e.w - (float)h3);
            unsigned xr = (unsigned)((c & 7) << 4);
            unsigned base = (unsigned)(c * 128) + (((unsigned)(q * 8)) ^ xr);
            *(uint2*)(eb + OFF_EH + base) = make_uint2(pk2(h0, h1), pk2(h2, h3));
            *(uint2*)(eb + OFF_EL + base) = make_uint2(pk2(l0, l1), pk2(l2, l3));
        }
        e2L[tid] = e2g[tid];
        s_hstL[tid] = 0u;
    }
    __syncthreads();

    // ---- P3: 8 code-blocks of 64; MFMA scores + in-register top-2 ----
    // D = A(E-codes) x B(X-rows): C col=lane&15 -> x-row; C row=(lane>>4)*4+j -> code.
    float s1_0 = INFINITY, s2_0 = INFINITY, s1_1 = INFINITY, s2_1 = INFINITY;
    int   i1_0 = 0, i2_0 = 0, i1_1 = 0, i2_1 = 0;
    const char* ebase = s_arena;

#define CT_ALL(M) M(0) M(1) M(2) M(3)
#define UPD(rt, s, ki) { \
    bool lt1 = (s) < s1_##rt; bool lt2 = (s) < s2_##rt; \
    s2_##rt = lt1 ? s1_##rt : (lt2 ? (s) : s2_##rt); \
    i2_##rt = lt1 ? i1_##rt : (lt2 ? (ki) : i2_##rt); \
    s1_##rt = lt1 ? (s) : s1_##rt; \
    i1_##rt = lt1 ? (ki) : i1_##rt; }

    for (int cb = 0; cb < 8; ++cb) {
        const int cbBase = cb * 64 + fq * 4;

#define LDE2(ct) f32x4 e2q##ct = *(const f32x4*)(e2L + cb * 64 + ct * 16 + fq * 4);
        CT_ALL(LDE2)
#undef LDE2

#define LDE(ct) \
        const int c##ct = cb * 64 + ct * 16 + fr; \
        const char* rb##ct = ebase + c##ct * 128; \
        const unsigned xr##ct = (unsigned)((c##ct & 7) << 4); \
        f16x8 eh##ct##_0 = *(const f16x8*)(rb##ct + OFF_EH + (((unsigned)(fq*16 +  0)) ^ xr##ct)); \
        f16x8 eh##ct##_1 = *(const f16x8*)(rb##ct + OFF_EH + (((unsigned)(fq*16 + 64)) ^ xr##ct)); \
        f16x8 el##ct##_0 = *(const f16x8*)(rb##ct + OFF_EL + (((unsigned)(fq*16 +  0)) ^ xr##ct)); \
        f16x8 el##ct##_1 = *(const f16x8*)(rb##ct + OFF_EL + (((unsigned)(fq*16 + 64)) ^ xr##ct));
        CT_ALL(LDE)
#undef LDE

#define ACC1(rt, ct) \
        f32x4 a##rt##_##ct = {0.f, 0.f, 0.f, 0.f}; \
        a##rt##_##ct = MFMA(eh##ct##_0, xh##rt##_0, a##rt##_##ct); \
        a##rt##_##ct = MFMA(eh##ct##_1, xh##rt##_1, a##rt##_##ct); \
        a##rt##_##ct = MFMA(el##ct##_0, xh##rt##_0, a##rt##_##ct); \
        a##rt##_##ct = MFMA(el##ct##_1, xh##rt##_1, a##rt##_##ct); \
        a##rt##_##ct = MFMA(eh##ct##_0, xl##rt##_0, a##rt##_##ct); \
        a##rt##_##ct = MFMA(eh##ct##_1, xl##rt##_1, a##rt##_##ct); \
        a##rt##_##ct = MFMA(el##ct##_0, xl##rt##_0, a##rt##_##ct); \
        a##rt##_##ct = MFMA(el##ct##_1, xl##rt##_1, a##rt##_##ct);
#define ACC_CT(ct) ACC1(0, ct) ACC1(1, ct)
        CT_ALL(ACC_CT)
#undef ACC_CT
#undef ACC1

#define SCJ(rt, ct, j) { \
        float s = fmaf(-2.f, a##rt##_##ct[j], e2q##ct[j]); \
        int ki = cbBase + ct * 16 + j; \
        UPD(rt, s, ki) }
#define SC4(rt, ct) SCJ(rt, ct, 0) SCJ(rt, ct, 1) SCJ(rt, ct, 2) SCJ(rt, ct, 3)
#define SC_CT(ct) SC4(0, ct) SC4(1, ct)
        CT_ALL(SC_CT)
#undef SC_CT
#undef SC4
#undef SCJ
    }

    // ---- P4: cross-lane top-2 merge (groups fq=0..3 see disjoint codes) ----
#define MERGE(rt, off) { \
    float b1 = __shfl_xor(s1_##rt, off); int bi1 = __shfl_xor(i1_##rt, off); \
    float b2 = __shfl_xor(s2_##rt, off); int bi2 = __shfl_xor(i2_##rt, off); \
    bool bf = (b1 < s1_##rt) || (b1 == s1_##rt && bi1 < i1_##rt); \
    float c1 = bf ? b1 : s1_##rt; int ci1 = bf ? bi1 : i1_##rt; \
    float lw = bf ? s1_##rt : b1; int lwi = bf ? i1_##rt : bi1; \
    float d2 = bf ? b2 : s2_##rt; int di2 = bf ? bi2 : i2_##rt; \
    bool ds = (d2 < lw) || (d2 == lw && di2 < lwi); \
    s1_##rt = c1; i1_##rt = ci1; \
    s2_##rt = ds ? d2 : lw; i2_##rt = ds ? di2 : lwi; }
    MERGE(0, 16) MERGE(0, 32) MERGE(1, 16) MERGE(1, 32)
#undef MERGE

    if (fq == 0) {
        int row = w * 32 + fr;
        s_idxL[row] = i1_0;
        s_refL[row] = (s2_0 - s1_0 < MARGIN) ? i2_0 : -1;
        s_idxL[row + 16] = i1_1;
        s_refL[row + 16] = (s2_1 - s1_1 < MARGIN) ? i2_1 : -1;
    }
    __syncthreads();

    // ---- P5: per-row outputs (tid<256 = one row each) ----
    float lsum = 0.f;
    if (tid < ROWS_PER_BLK) {
        const int n = blockIdx.x * ROWS_PER_BLK + tid;
        const int b = n >> 12, hw = n & 4095;
        const float* xin = in + (size_t)b * 262144 + hw;
        int i1 = s_idxL[tid];
        const int ir = s_refL[tid];
        if (ir >= 0) {   // fp64 refinement on near-ties (argmin fp64-exact)
            double dA = 0.0, dB = 0.0;
            const float* eA = emb + i1 * D;
            const float* eB = emb + ir * D;
            for (int d = 0; d < D; ++d) {
                double xv = (double)xin[d * 4096];
                double tA = xv - (double)eA[d]; dA = fma(tA, tA, dA);
                double tB = xv - (double)eB[d]; dB = fma(tB, tB, dB);
            }
            if (dB < dA || (dB == dA && ir < i1)) { i1 = ir; s_idxL[tid] = ir; }
        }
        atomicAdd(&s_hstL[i1], 1u);

        // quantized write (exact fp32 codebook row from global) + loss
        const float4* eq = (const float4*)(emb + (size_t)i1 * D);
        float* qout = quant_out + (size_t)b * 262144 + hw;
        #pragma unroll
        for (int i = 0; i < 16; ++i) {
            float4 q = eq[i];
            float x0 = xin[(4 * i + 0) * 4096], x1 = xin[(4 * i + 1) * 4096];
            float x2 = xin[(4 * i + 2) * 4096], x3 = xin[(4 * i + 3) * 4096];
            float d0 = q.x - x0; lsum = fmaf(d0, d0, lsum);
            float d1 = q.y - x1; lsum = fmaf(d1, d1, lsum);
            float d2 = q.z - x2; lsum = fmaf(d2, d2, lsum);
            float d3 = q.w - x3; lsum = fmaf(d3, d3, lsum);
            qout[(4 * i + 0) * 4096] = q.x; qout[(4 * i + 1) * 4096] = q.y;
            qout[(4 * i + 2) * 4096] = q.z; qout[(4 * i + 3) * 4096] = q.w;
        }
    }

    // block loss reduction (double) -> one deterministic fixed-point atomic
    s_redL[tid] = (tid < ROWS_PER_BLK) ? (double)lsum : 0.0;
    __syncthreads();
    for (int s = BLK / 2; s > 0; s >>= 1) {
        if (tid < s) s_redL[tid] += s_redL[tid + s];
        __syncthreads();
    }
    if (tid == 0) {
        unsigned long long q =
            (unsigned long long)(long long)llrint(s_redL[0] * 1073741824.0);
        atomicAdd(loss_acc, q);
    }

    // flush histogram (integer atomics: deterministic)
    {
        unsigned int c = s_hstL[tid];
        if (c) atomicAdd(&counts[tid], c);
    }

    // cooperative coalesced one-hot writes: 256 rows x 512 floats
    float* enc = enc_out + (size_t)blockIdx.x * (size_t)(ROWS_PER_BLK * K);
    const int grp = tid >> 7;           // 0..3
    const int col4 = (tid & 127) * 4;
    for (int rr = 0; rr < ROWS_PER_BLK; rr += 4) {
        int row = rr + grp;
        int ir = s_idxL[row];
        float4 v;
        v.x = (col4 + 0 == ir) ? 1.f : 0.f;
        v.y = (col4 + 1 == ir) ? 1.f : 0.f;
        v.z = (col4 + 2 == ir) ? 1.f : 0.f;
        v.w = (col4 + 3 == ir) ? 1.f : 0.f;
        *reinterpret_cast<float4*>(enc + (size_t)row * K + col4) = v;
    }
}

__global__ __launch_bounds__(512) void vq_final_kernel(
    const unsigned int* __restrict__ counts,
    const unsigned long long* __restrict__ loss_acc,
    float* __restrict__ out_loss,
    float* __restrict__ out_perp)
{
    __shared__ double sp[512];
    int t = threadIdx.x;
    double p = (double)counts[t] / (double)N_ROWS;
    sp[t] = p * log(p + 1e-10);
    __syncthreads();
    for (int s = 256; s > 0; s >>= 1) {
        if (t < s) sp[t] += sp[t + s];
        __syncthreads();
    }
    if (t == 0) {
        double ls = (double)(long long)(*loss_acc) * (1.0 / 1073741824.0);
        *out_loss = (float)(0.25 * ls / 8388608.0);
        *out_perp = (float)exp(-sp[0]);
    }
}

extern "C" void kernel_launch(void* const* d_in, const int* in_sizes, int n_in,
                              void* d_out, int out_size, void* d_ws, size_t ws_size,
                              hipStream_t stream) {
    const float* in  = (const float*)d_in[0];
    const float* emb = (const float*)d_in[1];
    float* out = (float*)d_out;

    unsigned int* counts = (unsigned int*)d_ws;
    unsigned long long* loss_acc = (unsigned long long*)((char*)d_ws + 2048);
    float* e2 = (float*)((char*)d_ws + 4096);

    hipMemsetAsync(d_ws, 0, 2056, stream);
    vq_e2_kernel<<<2, 256, 0, stream>>>(emb, e2);
    vq_main_kernel<<<GRID, BLK, 0, stream>>>(in, emb, e2, counts, loss_acc,
                                             out + 1, out + 8388610);
    vq_final_kernel<<<1, 512, 0, stream>>>(counts, loss_acc, out, out + 8388609);
}

// Round 10
// 150.367 us; speedup vs baseline: 3.0607x; 1.0664x over previous
//
#include <hip/hip_runtime.h>
#include <math.h>

#define N_ROWS 131072   // 32*64*64
#define D 64
#define K 512
#define BLK 512                       // 8 waves
#define ROWS_PER_BLK 512              // 64 rows per wave
#define GRID (N_ROWS / ROWS_PER_BLK)  // 256 -> exactly 1 block/CU, ONE round
#define MARGIN 4e-3f

// d_out layout (floats):
//   [0] loss ; [1..8388608] quantized NCHW ; [8388609] perplexity ;
//   [8388610..] encodings [131072,512]
// d_ws: [0,2048) counts u32[512]; [2048,2056) loss_acc u64 fixed-point;
//       [4096,6144) e2 f32[512]

typedef __attribute__((ext_vector_type(8))) _Float16 f16x8;
typedef __attribute__((ext_vector_type(4))) float    f32x4;

#define MFMA(a, b, c) __builtin_amdgcn_mfma_f32_16x16x32_f16((a), (b), (c), 0, 0, 0)

// LDS arena (143360 B): codebook region [0,131072) doubles as X staging.
#define OFF_EH   0        // [512 codes][128 B] fp16-hi, XOR-swizzled
#define OFF_EL   65536    // fp16-lo
#define OFF_XH   0        // phase A: [512 rows][64] fp16-hi (overwritten by EH)
#define OFF_XL   65536    // phase A: fp16-lo (overwritten by EL)
#define OFF_E2   131072   // f32[512]
#define OFF_IDX  133120   // i32[512]
#define OFF_REF  135168   // i32[512]
#define OFF_HIST 137216   // u32[512]
#define OFF_RED  139264   // f64[512]
#define ARENA_SZ 143360

__global__ __launch_bounds__(256) void vq_e2_kernel(
    const float* __restrict__ emb, float* __restrict__ e2)
{
    int k = blockIdx.x * blockDim.x + threadIdx.x;
    if (k < K) {
        const float* e = emb + k * D;
        float s = 0.f;
        #pragma unroll
        for (int d = 0; d < D; ++d) s = fmaf(e[d], e[d], s);
        e2[k] = s;
    }
}

__device__ __forceinline__ unsigned pk2(_Float16 a, _Float16 b) {
    return (unsigned)__builtin_bit_cast(unsigned short, a) |
           ((unsigned)__builtin_bit_cast(unsigned short, b) << 16);
}

#define CT_ALL(M) M(0) M(1) M(2) M(3)
#define UPD(rt, s, ki) { \
    bool lt1 = (s) < s1_##rt; bool lt2 = (s) < s2_##rt; \
    s2_##rt = lt1 ? s1_##rt : (lt2 ? (s) : s2_##rt); \
    i2_##rt = lt1 ? i1_##rt : (lt2 ? (ki) : i2_##rt); \
    s1_##rt = lt1 ? (s) : s1_##rt; \
    i1_##rt = lt1 ? (ki) : i1_##rt; }

// One distance pass over the full codebook for 32 rows (2 row-tiles of 16).
// Dekker fp16 split, 3 product terms (hi*hi, lo*hi, hi*lo; lo*lo ~1.5e-5
// << MARGIN dropped). C layout: col=lane&15 -> x-row; row=(lane>>4)*4+j -> code.
__device__ __forceinline__ void dist_pass(
    const char* ebase, const float* e2L, int fq, int fr,
    f16x8 xh0_0, f16x8 xh0_1, f16x8 xl0_0, f16x8 xl0_1,
    f16x8 xh1_0, f16x8 xh1_1, f16x8 xl1_0, f16x8 xl1_1,
    int* s_idxL, int* s_refL, int row0)
{
    float s1_0 = INFINITY, s2_0 = INFINITY, s1_1 = INFINITY, s2_1 = INFINITY;
    int   i1_0 = 0, i2_0 = 0, i1_1 = 0, i2_1 = 0;

    for (int cb = 0; cb < 8; ++cb) {
        const int cbBase = cb * 64 + fq * 4;

#define LDE2(ct) f32x4 e2q##ct = *(const f32x4*)(e2L + cb * 64 + ct * 16 + fq * 4);
        CT_ALL(LDE2)
#undef LDE2

#define LDE(ct) \
        const int c##ct = cb * 64 + ct * 16 + fr; \
        const char* rb##ct = ebase + c##ct * 128; \
        const unsigned xr##ct = (unsigned)((c##ct & 7) << 4); \
        f16x8 eh##ct##_0 = *(const f16x8*)(rb##ct + OFF_EH + (((unsigned)(fq*16 +  0)) ^ xr##ct)); \
        f16x8 eh##ct##_1 = *(const f16x8*)(rb##ct + OFF_EH + (((unsigned)(fq*16 + 64)) ^ xr##ct)); \
        f16x8 el##ct##_0 = *(const f16x8*)(rb##ct + OFF_EL + (((unsigned)(fq*16 +  0)) ^ xr##ct)); \
        f16x8 el##ct##_1 = *(const f16x8*)(rb##ct + OFF_EL + (((unsigned)(fq*16 + 64)) ^ xr##ct));
        CT_ALL(LDE)
#undef LDE

#define ACC1(rt, ct) \
        f32x4 a##rt##_##ct = {0.f, 0.f, 0.f, 0.f}; \
        a##rt##_##ct = MFMA(eh##ct##_0, xh##rt##_0, a##rt##_##ct); \
        a##rt##_##ct = MFMA(eh##ct##_1, xh##rt##_1, a##rt##_##ct); \
        a##rt##_##ct = MFMA(el##ct##_0, xh##rt##_0, a##rt##_##ct); \
        a##rt##_##ct = MFMA(el##ct##_1, xh##rt##_1, a##rt##_##ct); \
        a##rt##_##ct = MFMA(eh##ct##_0, xl##rt##_0, a##rt##_##ct); \
        a##rt##_##ct = MFMA(eh##ct##_1, xl##rt##_1, a##rt##_##ct);
#define ACC_CT(ct) ACC1(0, ct) ACC1(1, ct)
        CT_ALL(ACC_CT)
#undef ACC_CT
#undef ACC1

#define SCJ(rt, ct, j) { \
        float s = fmaf(-2.f, a##rt##_##ct[j], e2q##ct[j]); \
        int ki = cbBase + ct * 16 + j; \
        UPD(rt, s, ki) }
#define SC4(rt, ct) SCJ(rt, ct, 0) SCJ(rt, ct, 1) SCJ(rt, ct, 2) SCJ(rt, ct, 3)
#define SC_CT(ct) SC4(0, ct) SC4(1, ct)
        CT_ALL(SC_CT)
#undef SC_CT
#undef SC4
#undef SCJ
    }

    // cross-lane top-2 merge (fq groups 0..3 see disjoint codes)
#define MERGE(rt, off) { \
    float b1 = __shfl_xor(s1_##rt, off); int bi1 = __shfl_xor(i1_##rt, off); \
    float b2 = __shfl_xor(s2_##rt, off); int bi2 = __shfl_xor(i2_##rt, off); \
    bool bf = (b1 < s1_##rt) || (b1 == s1_##rt && bi1 < i1_##rt); \
    float c1 = bf ? b1 : s1_##rt; int ci1 = bf ? bi1 : i1_##rt; \
    float lw = bf ? s1_##rt : b1; int lwi = bf ? i1_##rt : bi1; \
    float d2 = bf ? b2 : s2_##rt; int di2 = bf ? bi2 : i2_##rt; \
    bool ds = (d2 < lw) || (d2 == lw && di2 < lwi); \
    s1_##rt = c1; i1_##rt = ci1; \
    s2_##rt = ds ? d2 : lw; i2_##rt = ds ? di2 : lwi; }
    MERGE(0, 16) MERGE(0, 32) MERGE(1, 16) MERGE(1, 32)
#undef MERGE

    if (fq == 0) {
        s_idxL[row0 + fr] = i1_0;
        s_refL[row0 + fr] = (s2_0 - s1_0 < MARGIN) ? i2_0 : -1;
        s_idxL[row0 + fr + 16] = i1_1;
        s_refL[row0 + fr + 16] = (s2_1 - s1_1 < MARGIN) ? i2_1 : -1;
    }
}

// Round-9 lesson: MFMA fixed the per-wave codebook streaming. Round-10:
// LDS(141KB) caps at 1 block/CU, so GRID=512 ran as TWO serialized rounds
// (~80 us each). This version does all 512 rows/block in ONE round
// (GRID=256): X frags for 4 row-tiles load before the codebook overwrite,
// distance runs as two register-resident passes.
__global__ __launch_bounds__(BLK, 2) void vq_main_kernel(
    const float* __restrict__ in,     // [32,64,64,64] NCHW
    const float* __restrict__ emb,    // [512,64]
    const float* __restrict__ e2g,    // [512]
    unsigned int* __restrict__ counts,
    unsigned long long* __restrict__ loss_acc,
    float* __restrict__ quant_out,    // NCHW
    float* __restrict__ enc_out)      // [N_ROWS, 512]
{
    __shared__ __align__(16) char s_arena[ARENA_SZ];
    float*        e2L    = (float*)(s_arena + OFF_E2);
    int*          s_idxL = (int*)(s_arena + OFF_IDX);
    int*          s_refL = (int*)(s_arena + OFF_REF);
    unsigned int* s_hstL = (unsigned int*)(s_arena + OFF_HIST);
    double*       s_redL = (double*)(s_arena + OFF_RED);

    const int tid  = threadIdx.x;
    const int lane = tid & 63;
    const int w    = tid >> 6;      // wave 0..7
    const int fr   = lane & 15;
    const int fq   = lane >> 4;

    // ---- P0: stage x split into LDS [512 rows][64] fp16 (XH hi, XL lo) ----
    {
        const int nn = blockIdx.x * ROWS_PER_BLK + tid;
        const int bb = nn >> 12, hww = nn & 4095;
        const float* xp = in + (size_t)bb * 262144 + hww;
        char* xhW = s_arena + OFF_XH;
        char* xlW = s_arena + OFF_XL;
        #pragma unroll
        for (int i = 0; i < 64; i += 2) {
            float f0 = xp[i * 4096];
            float f1 = xp[(i + 1) * 4096];
            _Float16 h0 = (_Float16)f0; _Float16 l0 = (_Float16)(f0 - (float)h0);
            _Float16 h1 = (_Float16)f1; _Float16 l1 = (_Float16)(f1 - (float)h1);
            unsigned off = (unsigned)(tid * 64 + i) * 2u;
            *(unsigned*)(xhW + off) = pk2(h0, h1);
            *(unsigned*)(xlW + off) = pk2(l0, l1);
        }
    }
    __syncthreads();

    // ---- P1: load ALL 4 row-tiles' X fragments (16 f16x8 = 64 VGPR) ----
    const _Float16* xhL = (const _Float16*)(s_arena + OFF_XH);
    const _Float16* xlL = (const _Float16*)(s_arena + OFF_XL);
    const int xr0 = w * 64 + fr;
#define LDXF(t) \
    f16x8 xh##t##_0 = *(const f16x8*)(xhL + (xr0 + t * 16) * 64 + fq * 8); \
    f16x8 xh##t##_1 = *(const f16x8*)(xhL + (xr0 + t * 16) * 64 + fq * 8 + 32); \
    f16x8 xl##t##_0 = *(const f16x8*)(xlL + (xr0 + t * 16) * 64 + fq * 8); \
    f16x8 xl##t##_1 = *(const f16x8*)(xlL + (xr0 + t * 16) * 64 + fq * 8 + 32);
    LDXF(0) LDXF(1) LDXF(2) LDXF(3)
#undef LDXF
    __syncthreads();

    // ---- P2: overwrite LDS with split codebook (XOR-swizzled rows) ----
    {
        char* eb = s_arena;
        #pragma unroll
        for (int it = 0; it < 16; ++it) {
            int j = tid + it * 512;            // float4 index, 0..8191
            int c = j >> 4, q = j & 15;        // code, quad-within-row
            float4 e = ((const float4*)emb)[j];
            _Float16 h0 = (_Float16)e.x; _Float16 l0 = (_Float16)(e.x - (float)h0);
            _Float16 h1 = (_Float16)e.y; _Float16 l1 = (_Float16)(e.y - (float)h1);
            _Float16 h2 = (_Float16)e.z; _Float16 l2 = (_Float16)(e.z - (float)h2);
            _Float16 h3 = (_Float16)e.w; _Float16 l3 = (_Float16)(e.w - (float)h3);
            unsigned xr = (unsigned)((c & 7) << 4);
            unsigned base = (unsigned)(c * 128) + (((unsigned)(q * 8)) ^ xr);
            *(uint2*)(eb + OFF_EH + base) = make_uint2(pk2(h0, h1), pk2(h2, h3));
            *(uint2*)(eb + OFF_EL + base) = make_uint2(pk2(l0, l1), pk2(l2, l3));
        }
        e2L[tid] = e2g[tid];
        s_hstL[tid] = 0u;
    }
    __syncthreads();

    // ---- P3: two distance passes (rows w*64+[0,32) then +[32,64)) ----
    dist_pass(s_arena, e2L, fq, fr,
              xh0_0, xh0_1, xl0_0, xl0_1, xh1_0, xh1_1, xl1_0, xl1_1,
              s_idxL, s_refL, w * 64);
    dist_pass(s_arena, e2L, fq, fr,
              xh2_0, xh2_1, xl2_0, xl2_1, xh3_0, xh3_1, xl3_0, xl3_1,
              s_idxL, s_refL, w * 64 + 32);
    __syncthreads();

    // ---- P5: per-row outputs (each thread = one row) ----
    float lsum = 0.f;
    {
        const int n = blockIdx.x * ROWS_PER_BLK + tid;
        const int b = n >> 12, hw = n & 4095;
        const float* xin = in + (size_t)b * 262144 + hw;
        int i1 = s_idxL[tid];
        const int ir = s_refL[tid];
        if (ir >= 0) {   // fp64 refinement on near-ties (argmin fp64-exact)
            double dA = 0.0, dB = 0.0;
            const float* eA = emb + i1 * D;
            const float* eB = emb + ir * D;
            for (int d = 0; d < D; ++d) {
                double xv = (double)xin[d * 4096];
                double tA = xv - (double)eA[d]; dA = fma(tA, tA, dA);
                double tB = xv - (double)eB[d]; dB = fma(tB, tB, dB);
            }
            if (dB < dA || (dB == dA && ir < i1)) { i1 = ir; s_idxL[tid] = ir; }
        }
        atomicAdd(&s_hstL[i1], 1u);

        // quantized write (exact fp32 codebook row from global) + loss
        const float4* eq = (const float4*)(emb + (size_t)i1 * D);
        float* qout = quant_out + (size_t)b * 262144 + hw;
        #pragma unroll
        for (int i = 0; i < 16; ++i) {
            float4 q = eq[i];
            float x0 = xin[(4 * i + 0) * 4096], x1 = xin[(4 * i + 1) * 4096];
            float x2 = xin[(4 * i + 2) * 4096], x3 = xin[(4 * i + 3) * 4096];
            float d0 = q.x - x0; lsum = fmaf(d0, d0, lsum);
            float d1 = q.y - x1; lsum = fmaf(d1, d1, lsum);
            float d2 = q.z - x2; lsum = fmaf(d2, d2, lsum);
            float d3 = q.w - x3; lsum = fmaf(d3, d3, lsum);
            qout[(4 * i + 0) * 4096] = q.x; qout[(4 * i + 1) * 4096] = q.y;
            qout[(4 * i + 2) * 4096] = q.z; qout[(4 * i + 3) * 4096] = q.w;
        }
    }

    // block loss reduction (double) -> one deterministic fixed-point atomic
    s_redL[tid] = (double)lsum;
    __syncthreads();
    for (int s = BLK / 2; s > 0; s >>= 1) {
        if (tid < s) s_redL[tid] += s_redL[tid + s];
        __syncthreads();
    }
    if (tid == 0) {
        unsigned long long q =
            (unsigned long long)(long long)llrint(s_redL[0] * 1073741824.0);
        atomicAdd(loss_acc, q);
    }

    // flush histogram (integer atomics: deterministic)
    {
        unsigned int c = s_hstL[tid];
        if (c) atomicAdd(&counts[tid], c);
    }

    // cooperative coalesced one-hot writes: 512 rows x 512 floats
    float* enc = enc_out + (size_t)blockIdx.x * (size_t)(ROWS_PER_BLK * K);
    const int grp = tid >> 7;           // 0..3
    const int col4 = (tid & 127) * 4;
    for (int rr = 0; rr < ROWS_PER_BLK; rr += 4) {
        int row = rr + grp;
        int ir = s_idxL[row];
        float4 v;
        v.x = (col4 + 0 == ir) ? 1.f : 0.f;
        v.y = (col4 + 1 == ir) ? 1.f : 0.f;
        v.z = (col4 + 2 == ir) ? 1.f : 0.f;
        v.w = (col4 + 3 == ir) ? 1.f : 0.f;
        *reinterpret_cast<float4*>(enc + (size_t)row * K + col4) = v;
    }
}

__global__ __launch_bounds__(512) void vq_final_kernel(
    const unsigned int* __restrict__ counts,
    const unsigned long long* __restrict__ loss_acc,
    float* __restrict__ out_loss,
    float* __restrict__ out_perp)
{
    __shared__ double sp[512];
    int t = threadIdx.x;
    double p = (double)counts[t] / (double)N_ROWS;
    sp[t] = p * log(p + 1e-10);
    __syncthreads();
    for (int s = 256; s > 0; s >>= 1) {
        if (t < s) sp[t] += sp[t + s];
        __syncthreads();
    }
    if (t == 0) {
        double ls = (double)(long long)(*loss_acc) * (1.0 / 1073741824.0);
        *out_loss = (float)(0.25 * ls / 8388608.0);
        *out_perp = (float)exp(-sp[0]);
    }
}

extern "C" void kernel_launch(void* const* d_in, const int* in_sizes, int n_in,
                              void* d_out, int out_size, void* d_ws, size_t ws_size,
                              hipStream_t stream) {
    const float* in  = (const float*)d_in[0];
    const float* emb = (const float*)d_in[1];
    float* out = (float*)d_out;

    unsigned int* counts = (unsigned int*)d_ws;
    unsigned long long* loss_acc = (unsigned long long*)((char*)d_ws + 2048);
    float* e2 = (float*)((char*)d_ws + 4096);

    hipMemsetAsync(d_ws, 0, 2056, stream);
    vq_e2_kernel<<<2, 256, 0, stream>>>(emb, e2);
    vq_main_kernel<<<GRID, BLK, 0, stream>>>(in, emb, e2, counts, loss_acc,
                                             out + 1, out + 8388610);
    vq_final_kernel<<<1, 512, 0, stream>>>(counts, loss_acc, out, out + 8388609);
}